// Round 1
// baseline (244.346 us; speedup 1.0000x reference)
//
#include <hip/hip_runtime.h>

namespace {

constexpr int kB = 2;
constexpr int kN = 65536;
constexpr int kK = 16;
constexpr int kD = 32;
constexpr int kPts = kB * kN;           // 131072 points
constexpr int kBND = kPts * kD;         // 4,194,304 elements per feature map
constexpr int kThreads = 256;
constexpr int kPtsPerBlk = 32;          // 8 lanes per point
constexpr int kBlocks = kPts / kPtsPerBlk;  // 4096
static_assert(kBlocks * kPtsPerBlk == kPts, "grid must tile points exactly");

__device__ __forceinline__ float relu_(float v) { return fmaxf(v, 0.f); }
__device__ __forceinline__ float lrelu_(float v) { return v >= 0.f ? v : 0.2f * v; }

// z[p,:] = relu((src[p,:] @ W2) * g2 + b2)   -- conv1 folded to per-point
__global__ __launch_bounds__(kThreads)
void zprep_kernel(const float* __restrict__ src, const float* __restrict__ W2,
                  const float* __restrict__ g2, const float* __restrict__ b2,
                  float* __restrict__ z)
{
    __shared__ alignas(16) float sW2[kD * kD];
    __shared__ float srow[kPtsPerBlk][kD + 1];
    __shared__ float sg2[kD], sb2[kD];
    const int tid = threadIdx.x;
    for (int i = tid; i < kD * kD; i += kThreads) sW2[i] = W2[i];
    if (tid < kD) { sg2[tid] = g2[tid]; sb2[tid] = b2[tid]; }
    const int s  = tid & 7;        // 16B slice within row
    const int pl = tid >> 3;       // local point
    const int point = blockIdx.x * kPtsPerBlk + pl;
    float4 v = reinterpret_cast<const float4*>(src)[point * 8 + s];
    srow[pl][s * 4 + 0] = v.x; srow[pl][s * 4 + 1] = v.y;
    srow[pl][s * 4 + 2] = v.z; srow[pl][s * 4 + 3] = v.w;
    __syncthreads();
    float ax = 0, ay = 0, az = 0, aw = 0;
#pragma unroll
    for (int d = 0; d < kD; ++d) {
        const float t = srow[pl][d];
        const float4 w = *reinterpret_cast<const float4*>(&sW2[d * kD + s * 4]);
        ax = fmaf(t, w.x, ax); ay = fmaf(t, w.y, ay);
        az = fmaf(t, w.z, az); aw = fmaf(t, w.w, aw);
    }
    float4 zr;
    zr.x = relu_(fmaf(ax, sg2[s * 4 + 0], sb2[s * 4 + 0]));
    zr.y = relu_(fmaf(ay, sg2[s * 4 + 1], sb2[s * 4 + 1]));
    zr.z = relu_(fmaf(az, sg2[s * 4 + 2], sb2[s * 4 + 2]));
    zr.w = relu_(fmaf(aw, sg2[s * 4 + 3], sb2[s * 4 + 3]));
    reinterpret_cast<float4*>(z)[point * 8 + s] = zr;
}

// One fused block: gather z -> max/mean -> conv2 (+BN fold) -> residual epilogue
// -> compute next layer's z row from t = lrelu(...)
// MODE: 0 = first (s:=y, cur:=y, t=lrelu(y))
//       1 = mid   (s+=y, t=lrelu(y+prev), cur:=y)
//       2 = mid   (s+=y, t=lrelu(y+prev), no cur store)
//       3 = last  (out = lrelu(s+y), no t / no z-next)
template <int MODE>
__global__ __launch_bounds__(kThreads)
void blk_kernel(const float* __restrict__ zsrc, const int* __restrict__ idx,
                const float* __restrict__ W1, const float* __restrict__ g1,
                const float* __restrict__ b1,
                const float* __restrict__ W2n, const float* __restrict__ g2n,
                const float* __restrict__ b2n,
                const float* __restrict__ prev, float* __restrict__ cur,
                float* __restrict__ sacc, float* __restrict__ znext)
{
    __shared__ alignas(16) float sW1[2 * kD * kD];
    __shared__ alignas(16) float sW2[kD * kD];
    __shared__ float scat[kPtsPerBlk][2 * kD + 1];
    __shared__ float stl[kPtsPerBlk][kD + 1];
    __shared__ float sg1[kD], sb1[kD], sg2[kD], sb2[kD];
    const int tid = threadIdx.x;
    for (int i = tid; i < 2 * kD * kD; i += kThreads) sW1[i] = W1[i];
    if (MODE != 3) {
        for (int i = tid; i < kD * kD; i += kThreads) sW2[i] = W2n[i];
    }
    if (tid < kD) {
        sg1[tid] = g1[tid]; sb1[tid] = b1[tid];
        if (MODE != 3) { sg2[tid] = g2n[tid]; sb2[tid] = b2n[tid]; }
    }
    const int s    = tid & 7;
    const int pl   = tid >> 3;
    const int lane = tid & 63;
    const int grp  = lane & ~7;
    const int point = blockIdx.x * kPtsPerBlk + pl;
    const int base  = (point >> 16) << 16;   // b * N  (N = 65536)
    const int2 pr = reinterpret_cast<const int2*>(idx)[point * 8 + s];  // idx[2s],idx[2s+1]
    __syncthreads();

    // gather + online max/sum over the 16 neighbours; lane handles 4 channels
    float mx0 = 0, mx1 = 0, mx2 = 0, mx3 = 0;   // relu output >= 0, so 0 is a safe max-identity
    float sm0 = 0, sm1 = 0, sm2 = 0, sm3 = 0;
#pragma unroll
    for (int k = 0; k < kK; ++k) {
        const int sel = (k & 1) ? pr.y : pr.x;
        const int row = __shfl(sel, grp + (k >> 1), 64);
        const float4 h = reinterpret_cast<const float4*>(zsrc)[(base + row) * 8 + s];
        mx0 = fmaxf(mx0, h.x); sm0 += h.x;
        mx1 = fmaxf(mx1, h.y); sm1 += h.y;
        mx2 = fmaxf(mx2, h.z); sm2 += h.z;
        mx3 = fmaxf(mx3, h.w); sm3 += h.w;
    }
    constexpr float inv = 1.f / kK;
    scat[pl][s * 4 + 0] = mx0; scat[pl][s * 4 + 1] = mx1;
    scat[pl][s * 4 + 2] = mx2; scat[pl][s * 4 + 3] = mx3;
    scat[pl][kD + s * 4 + 0] = sm0 * inv; scat[pl][kD + s * 4 + 1] = sm1 * inv;
    scat[pl][kD + s * 4 + 2] = sm2 * inv; scat[pl][kD + s * 4 + 3] = sm3 * inv;
    __syncthreads();

    // conv2: y = (cat @ W1) * g1 + b1
    float ax = 0, ay = 0, az = 0, aw = 0;
#pragma unroll
    for (int c = 0; c < 2 * kD; ++c) {
        const float cv = scat[pl][c];
        const float4 w = *reinterpret_cast<const float4*>(&sW1[c * kD + s * 4]);
        ax = fmaf(cv, w.x, ax); ay = fmaf(cv, w.y, ay);
        az = fmaf(cv, w.z, az); aw = fmaf(cv, w.w, aw);
    }
    float4 y;
    y.x = fmaf(ax, sg1[s * 4 + 0], sb1[s * 4 + 0]);
    y.y = fmaf(ay, sg1[s * 4 + 1], sb1[s * 4 + 1]);
    y.z = fmaf(az, sg1[s * 4 + 2], sb1[s * 4 + 2]);
    y.w = fmaf(aw, sg1[s * 4 + 3], sb1[s * 4 + 3]);

    const int rb = point * 8 + s;
    float4 t;
    if (MODE == 0) {
        reinterpret_cast<float4*>(sacc)[rb] = y;
        reinterpret_cast<float4*>(cur)[rb]  = y;
        t.x = lrelu_(y.x); t.y = lrelu_(y.y); t.z = lrelu_(y.z); t.w = lrelu_(y.w);
    } else if (MODE == 1 || MODE == 2) {
        float4 sa = reinterpret_cast<const float4*>(sacc)[rb];
        sa.x += y.x; sa.y += y.y; sa.z += y.z; sa.w += y.w;
        reinterpret_cast<float4*>(sacc)[rb] = sa;
        const float4 pv = reinterpret_cast<const float4*>(prev)[rb];
        t.x = lrelu_(y.x + pv.x); t.y = lrelu_(y.y + pv.y);
        t.z = lrelu_(y.z + pv.z); t.w = lrelu_(y.w + pv.w);
        if (MODE == 1) reinterpret_cast<float4*>(cur)[rb] = y;
    } else {  // MODE == 3: final output
        const float4 sa = reinterpret_cast<const float4*>(sacc)[rb];
        float4 o;
        o.x = lrelu_(sa.x + y.x); o.y = lrelu_(sa.y + y.y);
        o.z = lrelu_(sa.z + y.z); o.w = lrelu_(sa.w + y.w);
        reinterpret_cast<float4*>(sacc)[rb] = o;
        return;
    }

    // next layer's z row: z = relu((t @ W2n) * g2n + b2n)
    stl[pl][s * 4 + 0] = t.x; stl[pl][s * 4 + 1] = t.y;
    stl[pl][s * 4 + 2] = t.z; stl[pl][s * 4 + 3] = t.w;
    __syncthreads();
    float zx = 0, zy = 0, zz = 0, zw = 0;
#pragma unroll
    for (int d = 0; d < kD; ++d) {
        const float tv = stl[pl][d];
        const float4 w = *reinterpret_cast<const float4*>(&sW2[d * kD + s * 4]);
        zx = fmaf(tv, w.x, zx); zy = fmaf(tv, w.y, zy);
        zz = fmaf(tv, w.z, zz); zw = fmaf(tv, w.w, zw);
    }
    float4 zr;
    zr.x = relu_(fmaf(zx, sg2[s * 4 + 0], sb2[s * 4 + 0]));
    zr.y = relu_(fmaf(zy, sg2[s * 4 + 1], sb2[s * 4 + 1]));
    zr.z = relu_(fmaf(zz, sg2[s * 4 + 2], sb2[s * 4 + 2]));
    zr.w = relu_(fmaf(zw, sg2[s * 4 + 3], sb2[s * 4 + 3]));
    reinterpret_cast<float4*>(znext)[rb] = zr;
}

}  // namespace

extern "C" void kernel_launch(void* const* d_in, const int* in_sizes, int n_in,
                              void* d_out, int out_size, void* d_ws, size_t ws_size,
                              hipStream_t stream)
{
    const float* x   = (const float*)d_in[0];
    const int*   idx = (const int*)d_in[1];
    const float* W2d = (const float*)d_in[2];
    const float* g2  = (const float*)d_in[3];
    const float* b2  = (const float*)d_in[4];
    const float* W1d = (const float*)d_in[5];
    const float* g1  = (const float*)d_in[6];
    const float* b1  = (const float*)d_in[7];
    float* out = (float*)d_out;
    float* ws  = (float*)d_ws;

    float* zA = ws;                          // 16 MB each
    float* zB = ws + (size_t)kBND;
    float* cA = ws + 2 * (size_t)kBND;       // x1
    float* cB = ws + 3 * (size_t)kBND;       // x2

    const dim3 grid(kBlocks), blk(kThreads);
    // z1 = relu((x @ W2_0)*g2_0 + b2_0)
    zprep_kernel<<<grid, blk, 0, stream>>>(x, W2d, g2, b2, zA);
    // block 1: x1; s=x1; z2 from lrelu(x1) with layer-1 params
    blk_kernel<0><<<grid, blk, 0, stream>>>(zA, idx, W1d, g1, b1,
        W2d + 1 * kD * kD, g2 + 1 * kD, b2 + 1 * kD, nullptr, cA, out, zB);
    // block 2: x2; s+=x2; z3 from lrelu(x2+x1) with layer-2 params
    blk_kernel<1><<<grid, blk, 0, stream>>>(zB, idx,
        W1d + 1 * 2 * kD * kD, g1 + 1 * kD, b1 + 1 * kD,
        W2d + 2 * kD * kD, g2 + 2 * kD, b2 + 2 * kD, cA, cB, out, zA);
    // block 3: x3; s+=x3; z4 from lrelu(x3+x2) with layer-3 params
    blk_kernel<2><<<grid, blk, 0, stream>>>(zA, idx,
        W1d + 2 * 2 * kD * kD, g1 + 2 * kD, b1 + 2 * kD,
        W2d + 3 * kD * kD, g2 + 3 * kD, b2 + 3 * kD, cB, nullptr, out, zB);
    // block 4: x4; out = lrelu(s + x4)
    blk_kernel<3><<<grid, blk, 0, stream>>>(zB, idx,
        W1d + 3 * 2 * kD * kD, g1 + 3 * kD, b1 + 3 * kD,
        nullptr, nullptr, nullptr, nullptr, nullptr, out, nullptr);
}

// Round 3
// 242.938 us; speedup vs baseline: 1.0058x; 1.0058x over previous
//
#include <hip/hip_runtime.h>
#include <hip/hip_cooperative_groups.h>

namespace cg = cooperative_groups;

namespace {

constexpr int kN = 65536;
constexpr int kK = 16;
constexpr int kD = 32;
constexpr int kPts = 2 * kN;              // 131072 points (B*N)
constexpr int kBND = kPts * kD;           // elements per feature map
constexpr int kThreads = 256;
constexpr int kPtsPerTile = 32;           // 8 lanes per point
constexpr int kGrid = 1024;               // 4 blocks/CU target
constexpr int kTiles = kPts / (kGrid * kPtsPerTile);   // 4 tiles/block
constexpr int kPtsPerBlock = kTiles * kPtsPerTile;     // 128 points/block
constexpr int kCUs = 256;
static_assert(kGrid * kPtsPerBlock == kPts, "tiling must cover all points");
static_assert(kN % kPtsPerBlock == 0, "blocks must not straddle batch boundary");

__device__ __forceinline__ float relu_(float v) { return fmaxf(v, 0.f); }
__device__ __forceinline__ float lrelu_(float v) { return v >= 0.f ? v : 0.2f * v; }

// ---------------------------------------------------------------------------
// Cooperative fused path: LDS holds only weights (12.8 KB/block) so the
// runtime's (64 KB-assuming) occupancy math still grants >=4 blocks/CU.
// Row vectors are broadcast across each point's 8-lane group via __shfl.
// ---------------------------------------------------------------------------
struct SmemW {
    alignas(16) float sW1[2 * kD * kD];   // 8192 B
    alignas(16) float sW2[kD * kD];       // 4096 B
    float sg1[kD], sb1[kD], sg2[kD], sb2[kD];  // 512 B
};

// out[c4..c4+3] = (vin spread over the 8-lane group, i.e. a 32-vector) @ W(32x32)
// W row-major in LDS; all lanes read broadcast-friendly addresses.
__device__ __forceinline__ float4 mat32_apply(const float4 vin, const float* __restrict__ W,
                                              int grp, int c4)
{
    float ax = 0, ay = 0, az = 0, aw = 0;
#pragma unroll
    for (int j = 0; j < 8; ++j) {
        const int sl = grp + j;
        const float t0 = __shfl(vin.x, sl, 64);
        const float t1 = __shfl(vin.y, sl, 64);
        const float t2 = __shfl(vin.z, sl, 64);
        const float t3 = __shfl(vin.w, sl, 64);
        const float4 w0 = *reinterpret_cast<const float4*>(&W[(4 * j + 0) * kD + c4]);
        const float4 w1 = *reinterpret_cast<const float4*>(&W[(4 * j + 1) * kD + c4]);
        const float4 w2 = *reinterpret_cast<const float4*>(&W[(4 * j + 2) * kD + c4]);
        const float4 w3 = *reinterpret_cast<const float4*>(&W[(4 * j + 3) * kD + c4]);
        ax = fmaf(t0, w0.x, ax); ay = fmaf(t0, w0.y, ay);
        az = fmaf(t0, w0.z, az); aw = fmaf(t0, w0.w, aw);
        ax = fmaf(t1, w1.x, ax); ay = fmaf(t1, w1.y, ay);
        az = fmaf(t1, w1.z, az); aw = fmaf(t1, w1.w, aw);
        ax = fmaf(t2, w2.x, ax); ay = fmaf(t2, w2.y, ay);
        az = fmaf(t2, w2.z, az); aw = fmaf(t2, w2.w, aw);
        ax = fmaf(t3, w3.x, ax); ay = fmaf(t3, w3.y, ay);
        az = fmaf(t3, w3.z, az); aw = fmaf(t3, w3.w, aw);
    }
    return make_float4(ax, ay, az, aw);
}

// One residual block. MODE: 0=first, 1=middle, 2=last.
template <int MODE>
__device__ __forceinline__ void coop_layer(
    const float* __restrict__ zsrc,
    const float* __restrict__ W1, const float* __restrict__ g1,
    const float* __restrict__ b1,
    const float* __restrict__ W2n, const float* __restrict__ g2n,
    const float* __restrict__ b2n,
    float* __restrict__ dst,
    int tid, int s, int pl, int grp, int blockBase,
    int2 (&pr)[kTiles], float4 (&sacc)[kTiles], float4 (&prev)[kTiles],
    SmemW& sm)
{
    // grid.sync() before entry guarantees previous layer's readers are done.
    for (int i = tid; i < 2 * kD * kD; i += kThreads) sm.sW1[i] = W1[i];
    if (MODE != 2) {
        for (int i = tid; i < kD * kD; i += kThreads) sm.sW2[i] = W2n[i];
    }
    if (tid < kD) {
        sm.sg1[tid] = g1[tid]; sm.sb1[tid] = b1[tid];
        if (MODE != 2) { sm.sg2[tid] = g2n[tid]; sm.sb2[tid] = b2n[tid]; }
    }
    __syncthreads();
    const int c4 = s * 4;

#pragma unroll
    for (int t = 0; t < kTiles; ++t) {
        const int point = blockBase + t * kPtsPerTile + pl;
        const int base  = point & ~(kN - 1);   // batch offset (b * N)
        const int2 p    = pr[t];

        // gather + online max/sum over 16 neighbours; lane owns 4 channels
        float mx0 = 0, mx1 = 0, mx2 = 0, mx3 = 0;  // relu output >= 0
        float sm0 = 0, sm1 = 0, sm2 = 0, sm3 = 0;
#pragma unroll
        for (int k = 0; k < kK; ++k) {
            const int sel = (k & 1) ? p.y : p.x;
            const int row = __shfl(sel, grp + (k >> 1), 64);
            const float4 h =
                reinterpret_cast<const float4*>(zsrc)[(base + row) * 8 + s];
            mx0 = fmaxf(mx0, h.x); sm0 += h.x;
            mx1 = fmaxf(mx1, h.y); sm1 += h.y;
            mx2 = fmaxf(mx2, h.z); sm2 += h.z;
            mx3 = fmaxf(mx3, h.w); sm3 += h.w;
        }
        constexpr float inv = 1.f / kK;
        const float4 mxv = make_float4(mx0, mx1, mx2, mx3);
        const float4 mnv = make_float4(sm0 * inv, sm1 * inv, sm2 * inv, sm3 * inv);

        // conv2: y = (cat(max, mean) @ W1) * g1 + b1
        const float4 ya = mat32_apply(mxv, sm.sW1, grp, c4);
        const float4 yb = mat32_apply(mnv, sm.sW1 + kD * kD, grp, c4);
        float4 y;
        y.x = fmaf(ya.x + yb.x, sm.sg1[c4 + 0], sm.sb1[c4 + 0]);
        y.y = fmaf(ya.y + yb.y, sm.sg1[c4 + 1], sm.sb1[c4 + 1]);
        y.z = fmaf(ya.z + yb.z, sm.sg1[c4 + 2], sm.sb1[c4 + 2]);
        y.w = fmaf(ya.w + yb.w, sm.sg1[c4 + 3], sm.sb1[c4 + 3]);

        const int rb = point * 8 + s;
        float4 tl;
        if (MODE == 0) {
            sacc[t] = y;
            prev[t] = y;
            tl.x = lrelu_(y.x); tl.y = lrelu_(y.y);
            tl.z = lrelu_(y.z); tl.w = lrelu_(y.w);
        } else if (MODE == 1) {
            sacc[t].x += y.x; sacc[t].y += y.y;
            sacc[t].z += y.z; sacc[t].w += y.w;
            tl.x = lrelu_(y.x + prev[t].x); tl.y = lrelu_(y.y + prev[t].y);
            tl.z = lrelu_(y.z + prev[t].z); tl.w = lrelu_(y.w + prev[t].w);
            prev[t] = y;
        } else {  // MODE == 2: final output = lrelu(sacc + y)
            float4 o;
            o.x = lrelu_(sacc[t].x + y.x); o.y = lrelu_(sacc[t].y + y.y);
            o.z = lrelu_(sacc[t].z + y.z); o.w = lrelu_(sacc[t].w + y.w);
            reinterpret_cast<float4*>(dst)[rb] = o;
            continue;
        }

        // next layer's z row: z = relu((tl @ W2n) * g2n + b2n)
        const float4 zp = mat32_apply(tl, sm.sW2, grp, c4);
        float4 zr;
        zr.x = relu_(fmaf(zp.x, sm.sg2[c4 + 0], sm.sb2[c4 + 0]));
        zr.y = relu_(fmaf(zp.y, sm.sg2[c4 + 1], sm.sb2[c4 + 1]));
        zr.z = relu_(fmaf(zp.z, sm.sg2[c4 + 2], sm.sb2[c4 + 2]));
        zr.w = relu_(fmaf(zp.w, sm.sg2[c4 + 3], sm.sb2[c4 + 3]));
        reinterpret_cast<float4*>(dst)[rb] = zr;
    }
}

__global__ __launch_bounds__(kThreads, 4)
void fused_kernel(const float* __restrict__ x, const int* __restrict__ idx,
                  const float* __restrict__ W2d, const float* __restrict__ g2,
                  const float* __restrict__ b2, const float* __restrict__ W1d,
                  const float* __restrict__ g1, const float* __restrict__ b1,
                  float* __restrict__ zA, float* __restrict__ zB,
                  float* __restrict__ out)
{
    cg::grid_group grid = cg::this_grid();
    __shared__ SmemW sm;

    const int tid = threadIdx.x;
    const int s   = tid & 7;          // 16 B slice within a 128 B row
    const int pl  = tid >> 3;         // local point within tile
    const int grp = (tid & 63) & ~7;  // wave-local 8-lane group base
    const int c4  = s * 4;
    const int blockBase = blockIdx.x * kPtsPerBlock;

    int2   pr[kTiles];
    float4 sacc[kTiles];
    float4 prev[kTiles];

    // ---- Phase 0: z1 = relu((x @ W2_0) * g2_0 + b2_0); load idx once ----
    for (int i = tid; i < kD * kD; i += kThreads) sm.sW2[i] = W2d[i];
    if (tid < kD) { sm.sg2[tid] = g2[tid]; sm.sb2[tid] = b2[tid]; }
    __syncthreads();
#pragma unroll
    for (int t = 0; t < kTiles; ++t) {
        const int point = blockBase + t * kPtsPerTile + pl;
        pr[t] = reinterpret_cast<const int2*>(idx)[point * 8 + s];
        const float4 v = reinterpret_cast<const float4*>(x)[point * 8 + s];
        const float4 zp = mat32_apply(v, sm.sW2, grp, c4);
        float4 zr;
        zr.x = relu_(fmaf(zp.x, sm.sg2[c4 + 0], sm.sb2[c4 + 0]));
        zr.y = relu_(fmaf(zp.y, sm.sg2[c4 + 1], sm.sb2[c4 + 1]));
        zr.z = relu_(fmaf(zp.z, sm.sg2[c4 + 2], sm.sb2[c4 + 2]));
        zr.w = relu_(fmaf(zp.w, sm.sg2[c4 + 3], sm.sb2[c4 + 3]));
        reinterpret_cast<float4*>(zA)[point * 8 + s] = zr;
    }
    grid.sync();

    coop_layer<0>(zA, W1d, g1, b1,
                  W2d + 1 * kD * kD, g2 + 1 * kD, b2 + 1 * kD, zB,
                  tid, s, pl, grp, blockBase, pr, sacc, prev, sm);
    grid.sync();
    coop_layer<1>(zB, W1d + 1 * 2 * kD * kD, g1 + 1 * kD, b1 + 1 * kD,
                  W2d + 2 * kD * kD, g2 + 2 * kD, b2 + 2 * kD, zA,
                  tid, s, pl, grp, blockBase, pr, sacc, prev, sm);
    grid.sync();
    coop_layer<1>(zA, W1d + 2 * 2 * kD * kD, g1 + 2 * kD, b1 + 2 * kD,
                  W2d + 3 * kD * kD, g2 + 3 * kD, b2 + 3 * kD, zB,
                  tid, s, pl, grp, blockBase, pr, sacc, prev, sm);
    grid.sync();
    coop_layer<2>(zB, W1d + 3 * 2 * kD * kD, g1 + 3 * kD, b1 + 3 * kD,
                  nullptr, nullptr, nullptr, out,
                  tid, s, pl, grp, blockBase, pr, sacc, prev, sm);
}

// ---------------------------------------------------------------------------
// Fallback path: the proven Round-1 five-dispatch pipeline (244 us).
// ---------------------------------------------------------------------------
constexpr int kFThreads = 256;
constexpr int kFPtsPerBlk = 32;
constexpr int kFBlocks = kPts / kFPtsPerBlk;

__global__ __launch_bounds__(kFThreads)
void zprep_kernel(const float* __restrict__ src, const float* __restrict__ W2,
                  const float* __restrict__ g2, const float* __restrict__ b2,
                  float* __restrict__ z)
{
    __shared__ alignas(16) float sW2[kD * kD];
    __shared__ float srow[kFPtsPerBlk][kD + 1];
    __shared__ float sg2[kD], sb2[kD];
    const int tid = threadIdx.x;
    for (int i = tid; i < kD * kD; i += kFThreads) sW2[i] = W2[i];
    if (tid < kD) { sg2[tid] = g2[tid]; sb2[tid] = b2[tid]; }
    const int s  = tid & 7;
    const int pl = tid >> 3;
    const int point = blockIdx.x * kFPtsPerBlk + pl;
    float4 v = reinterpret_cast<const float4*>(src)[point * 8 + s];
    srow[pl][s * 4 + 0] = v.x; srow[pl][s * 4 + 1] = v.y;
    srow[pl][s * 4 + 2] = v.z; srow[pl][s * 4 + 3] = v.w;
    __syncthreads();
    float ax = 0, ay = 0, az = 0, aw = 0;
#pragma unroll
    for (int d = 0; d < kD; ++d) {
        const float t = srow[pl][d];
        const float4 w = *reinterpret_cast<const float4*>(&sW2[d * kD + s * 4]);
        ax = fmaf(t, w.x, ax); ay = fmaf(t, w.y, ay);
        az = fmaf(t, w.z, az); aw = fmaf(t, w.w, aw);
    }
    float4 zr;
    zr.x = relu_(fmaf(ax, sg2[s * 4 + 0], sb2[s * 4 + 0]));
    zr.y = relu_(fmaf(ay, sg2[s * 4 + 1], sb2[s * 4 + 1]));
    zr.z = relu_(fmaf(az, sg2[s * 4 + 2], sb2[s * 4 + 2]));
    zr.w = relu_(fmaf(aw, sg2[s * 4 + 3], sb2[s * 4 + 3]));
    reinterpret_cast<float4*>(z)[point * 8 + s] = zr;
}

template <int MODE>
__global__ __launch_bounds__(kFThreads)
void blk_kernel(const float* __restrict__ zsrc, const int* __restrict__ idx,
                const float* __restrict__ W1, const float* __restrict__ g1,
                const float* __restrict__ b1,
                const float* __restrict__ W2n, const float* __restrict__ g2n,
                const float* __restrict__ b2n,
                const float* __restrict__ prev, float* __restrict__ cur,
                float* __restrict__ sacc, float* __restrict__ znext)
{
    __shared__ alignas(16) float sW1[2 * kD * kD];
    __shared__ alignas(16) float sW2[kD * kD];
    __shared__ float scat[kFPtsPerBlk][2 * kD + 1];
    __shared__ float stl[kFPtsPerBlk][kD + 1];
    __shared__ float sg1[kD], sb1[kD], sg2[kD], sb2[kD];
    const int tid = threadIdx.x;
    for (int i = tid; i < 2 * kD * kD; i += kFThreads) sW1[i] = W1[i];
    if (MODE != 3) {
        for (int i = tid; i < kD * kD; i += kFThreads) sW2[i] = W2n[i];
    }
    if (tid < kD) {
        sg1[tid] = g1[tid]; sb1[tid] = b1[tid];
        if (MODE != 3) { sg2[tid] = g2n[tid]; sb2[tid] = b2n[tid]; }
    }
    const int s    = tid & 7;
    const int pl   = tid >> 3;
    const int grp  = (tid & 63) & ~7;
    const int point = blockIdx.x * kFPtsPerBlk + pl;
    const int base  = point & ~(kN - 1);
    const int2 p = reinterpret_cast<const int2*>(idx)[point * 8 + s];
    __syncthreads();

    float mx0 = 0, mx1 = 0, mx2 = 0, mx3 = 0;
    float sm0 = 0, sm1 = 0, sm2 = 0, sm3 = 0;
#pragma unroll
    for (int k = 0; k < kK; ++k) {
        const int sel = (k & 1) ? p.y : p.x;
        const int row = __shfl(sel, grp + (k >> 1), 64);
        const float4 h = reinterpret_cast<const float4*>(zsrc)[(base + row) * 8 + s];
        mx0 = fmaxf(mx0, h.x); sm0 += h.x;
        mx1 = fmaxf(mx1, h.y); sm1 += h.y;
        mx2 = fmaxf(mx2, h.z); sm2 += h.z;
        mx3 = fmaxf(mx3, h.w); sm3 += h.w;
    }
    constexpr float inv = 1.f / kK;
    scat[pl][s * 4 + 0] = mx0; scat[pl][s * 4 + 1] = mx1;
    scat[pl][s * 4 + 2] = mx2; scat[pl][s * 4 + 3] = mx3;
    scat[pl][kD + s * 4 + 0] = sm0 * inv; scat[pl][kD + s * 4 + 1] = sm1 * inv;
    scat[pl][kD + s * 4 + 2] = sm2 * inv; scat[pl][kD + s * 4 + 3] = sm3 * inv;
    __syncthreads();

    float ax = 0, ay = 0, az = 0, aw = 0;
#pragma unroll
    for (int c = 0; c < 2 * kD; ++c) {
        const float cv = scat[pl][c];
        const float4 w = *reinterpret_cast<const float4*>(&sW1[c * kD + s * 4]);
        ax = fmaf(cv, w.x, ax); ay = fmaf(cv, w.y, ay);
        az = fmaf(cv, w.z, az); aw = fmaf(cv, w.w, aw);
    }
    float4 y;
    y.x = fmaf(ax, sg1[s * 4 + 0], sb1[s * 4 + 0]);
    y.y = fmaf(ay, sg1[s * 4 + 1], sb1[s * 4 + 1]);
    y.z = fmaf(az, sg1[s * 4 + 2], sb1[s * 4 + 2]);
    y.w = fmaf(aw, sg1[s * 4 + 3], sb1[s * 4 + 3]);

    const int rb = point * 8 + s;
    float4 t;
    if (MODE == 0) {
        reinterpret_cast<float4*>(sacc)[rb] = y;
        reinterpret_cast<float4*>(cur)[rb]  = y;
        t.x = lrelu_(y.x); t.y = lrelu_(y.y); t.z = lrelu_(y.z); t.w = lrelu_(y.w);
    } else if (MODE == 1 || MODE == 2) {
        float4 sa = reinterpret_cast<const float4*>(sacc)[rb];
        sa.x += y.x; sa.y += y.y; sa.z += y.z; sa.w += y.w;
        reinterpret_cast<float4*>(sacc)[rb] = sa;
        const float4 pv = reinterpret_cast<const float4*>(prev)[rb];
        t.x = lrelu_(y.x + pv.x); t.y = lrelu_(y.y + pv.y);
        t.z = lrelu_(y.z + pv.z); t.w = lrelu_(y.w + pv.w);
        if (MODE == 1) reinterpret_cast<float4*>(cur)[rb] = y;
    } else {
        const float4 sa = reinterpret_cast<const float4*>(sacc)[rb];
        float4 o;
        o.x = lrelu_(sa.x + y.x); o.y = lrelu_(sa.y + y.y);
        o.z = lrelu_(sa.z + y.z); o.w = lrelu_(sa.w + y.w);
        reinterpret_cast<float4*>(sacc)[rb] = o;
        return;
    }

    stl[pl][s * 4 + 0] = t.x; stl[pl][s * 4 + 1] = t.y;
    stl[pl][s * 4 + 2] = t.z; stl[pl][s * 4 + 3] = t.w;
    __syncthreads();
    float zx = 0, zy = 0, zz = 0, zw = 0;
#pragma unroll
    for (int d = 0; d < kD; ++d) {
        const float tv = stl[pl][d];
        const float4 w = *reinterpret_cast<const float4*>(&sW2[d * kD + s * 4]);
        zx = fmaf(tv, w.x, zx); zy = fmaf(tv, w.y, zy);
        zz = fmaf(tv, w.z, zz); zw = fmaf(tv, w.w, zw);
    }
    float4 zr;
    zr.x = relu_(fmaf(zx, sg2[s * 4 + 0], sb2[s * 4 + 0]));
    zr.y = relu_(fmaf(zy, sg2[s * 4 + 1], sb2[s * 4 + 1]));
    zr.z = relu_(fmaf(zz, sg2[s * 4 + 2], sb2[s * 4 + 2]));
    zr.w = relu_(fmaf(zw, sg2[s * 4 + 3], sb2[s * 4 + 3]));
    reinterpret_cast<float4*>(znext)[rb] = zr;
}

}  // namespace

extern "C" void kernel_launch(void* const* d_in, const int* in_sizes, int n_in,
                              void* d_out, int out_size, void* d_ws, size_t ws_size,
                              hipStream_t stream)
{
    const float* x   = (const float*)d_in[0];
    const int*   idx = (const int*)d_in[1];
    const float* W2d = (const float*)d_in[2];
    const float* g2  = (const float*)d_in[3];
    const float* b2  = (const float*)d_in[4];
    const float* W1d = (const float*)d_in[5];
    const float* g1  = (const float*)d_in[6];
    const float* b1  = (const float*)d_in[7];
    float* out = (float*)d_out;
    float* ws  = (float*)d_ws;

    float* zA = ws;                          // 16 MB each
    float* zB = ws + (size_t)kBND;
    float* cA = ws + 2 * (size_t)kBND;
    float* cB = ws + 3 * (size_t)kBND;

    // Host-side occupancy probe (deterministic, capture-safe): only take the
    // cooperative path if the runtime will actually admit kGrid blocks.
    int nb = 0;
    hipError_t qe = hipOccupancyMaxActiveBlocksPerMultiprocessor(
        &nb, reinterpret_cast<const void*>(&fused_kernel), kThreads, 0);
    const bool coop_ok = (qe == hipSuccess) && (nb * kCUs >= kGrid);

    if (coop_ok) {
        void* args[] = { (void*)&x, (void*)&idx, (void*)&W2d, (void*)&g2,
                         (void*)&b2, (void*)&W1d, (void*)&g1, (void*)&b1,
                         (void*)&zA, (void*)&zB, (void*)&out };
        hipError_t le = hipLaunchCooperativeKernel(
            (const void*)fused_kernel, dim3(kGrid), dim3(kThreads), args, 0, stream);
        if (le == hipSuccess) return;
        // fall through to the proven multi-dispatch path on any launch failure
    }

    const dim3 grid(kFBlocks), blk(kFThreads);
    zprep_kernel<<<grid, blk, 0, stream>>>(x, W2d, g2, b2, zA);
    blk_kernel<0><<<grid, blk, 0, stream>>>(zA, idx, W1d, g1, b1,
        W2d + 1 * kD * kD, g2 + 1 * kD, b2 + 1 * kD, nullptr, cA, out, zB);
    blk_kernel<1><<<grid, blk, 0, stream>>>(zB, idx,
        W1d + 1 * 2 * kD * kD, g1 + 1 * kD, b1 + 1 * kD,
        W2d + 2 * kD * kD, g2 + 2 * kD, b2 + 2 * kD, cA, cB, out, zA);
    blk_kernel<2><<<grid, blk, 0, stream>>>(zA, idx,
        W1d + 2 * 2 * kD * kD, g1 + 2 * kD, b1 + 2 * kD,
        W2d + 3 * kD * kD, g2 + 3 * kD, b2 + 3 * kD, cB, nullptr, out, zB);
    blk_kernel<3><<<grid, blk, 0, stream>>>(zB, idx,
        W1d + 3 * 2 * kD * kD, g1 + 3 * kD, b1 + 3 * kD,
        nullptr, nullptr, nullptr, nullptr, nullptr, out, nullptr);
}

// Round 4
// 215.435 us; speedup vs baseline: 1.1342x; 1.1277x over previous
//
#include <hip/hip_runtime.h>
#include <hip/hip_fp16.h>

namespace {

constexpr int kN = 65536;
constexpr int kK = 16;
constexpr int kD = 32;
constexpr int kPts = 2 * kN;                 // 131072 points (B*N)
constexpr int kThreads = 256;
constexpr int kPtsPerBlk = 32;               // 8 lanes per point
constexpr int kBlocks = kPts / kPtsPerBlk;   // 4096
static_assert(kBlocks * kPtsPerBlk == kPts, "grid must tile points exactly");

__device__ __forceinline__ float relu_(float v) { return fmaxf(v, 0.f); }
__device__ __forceinline__ float lrelu_(float v) { return v >= 0.f ? v : 0.2f * v; }

// pack float4 -> 4 fp16 in a uint2
__device__ __forceinline__ uint2 pack_h4(float a, float b, float c, float d) {
    const __half2 h0 = __floats2half2_rn(a, b);
    const __half2 h1 = __floats2half2_rn(c, d);
    uint2 u;
    u.x = *reinterpret_cast<const unsigned int*>(&h0);
    u.y = *reinterpret_cast<const unsigned int*>(&h1);
    return u;
}

// unpack uint2 (4 fp16) -> float4
__device__ __forceinline__ float4 unpack_h4(uint2 u) {
    const __half2 h0 = *reinterpret_cast<const __half2*>(&u.x);
    const __half2 h1 = *reinterpret_cast<const __half2*>(&u.y);
    const float2 f0 = __half22float2(h0);
    const float2 f1 = __half22float2(h1);
    return make_float4(f0.x, f0.y, f1.x, f1.y);
}

// z1 = relu((x @ W2_0)*g2_0 + b2_0) in fp16; also pack idx into uint16 pairs.
__global__ __launch_bounds__(kThreads)
void zprep_kernel(const float* __restrict__ src, const int* __restrict__ idx,
                  const float* __restrict__ W2, const float* __restrict__ g2,
                  const float* __restrict__ b2,
                  uint2* __restrict__ z, unsigned int* __restrict__ idx16)
{
    __shared__ alignas(16) float sW2[kD * kD];
    __shared__ float srow[kPtsPerBlk][kD + 1];
    __shared__ float sg2[kD], sb2[kD];
    const int tid = threadIdx.x;
    for (int i = tid; i < kD * kD; i += kThreads) sW2[i] = W2[i];
    if (tid < kD) { sg2[tid] = g2[tid]; sb2[tid] = b2[tid]; }
    const int s  = tid & 7;        // slice within row
    const int pl = tid >> 3;       // local point
    const int point = blockIdx.x * kPtsPerBlk + pl;

    // pack two neighbour indices (each < 65536) into one uint
    const int2 p = reinterpret_cast<const int2*>(idx)[point * 8 + s];
    idx16[point * 8 + s] = (unsigned int)(p.x & 0xFFFF) | ((unsigned int)p.y << 16);

    float4 v = reinterpret_cast<const float4*>(src)[point * 8 + s];
    srow[pl][s * 4 + 0] = v.x; srow[pl][s * 4 + 1] = v.y;
    srow[pl][s * 4 + 2] = v.z; srow[pl][s * 4 + 3] = v.w;
    __syncthreads();
    float ax = 0, ay = 0, az = 0, aw = 0;
#pragma unroll
    for (int d = 0; d < kD; ++d) {
        const float t = srow[pl][d];
        const float4 w = *reinterpret_cast<const float4*>(&sW2[d * kD + s * 4]);
        ax = fmaf(t, w.x, ax); ay = fmaf(t, w.y, ay);
        az = fmaf(t, w.z, az); aw = fmaf(t, w.w, aw);
    }
    z[point * 8 + s] = pack_h4(
        relu_(fmaf(ax, sg2[s * 4 + 0], sb2[s * 4 + 0])),
        relu_(fmaf(ay, sg2[s * 4 + 1], sb2[s * 4 + 1])),
        relu_(fmaf(az, sg2[s * 4 + 2], sb2[s * 4 + 2])),
        relu_(fmaf(aw, sg2[s * 4 + 3], sb2[s * 4 + 3])));
}

// One fused residual block. MODE: 0=first (sacc:=y, cur:=y, t=lrelu(y))
//                                1=mid   (sacc+=y, t=lrelu(y+prev), cur:=y)
//                                2=mid   (sacc+=y, t=lrelu(y+prev), no cur)
//                                3=last  (out = lrelu(sacc+y))
// z / cur / prev are fp16 (uint2 = 4 halves per lane); sacc/out fp32.
template <int MODE>
__global__ __launch_bounds__(kThreads)
void blk_kernel(const uint2* __restrict__ zsrc, const unsigned int* __restrict__ idx16,
                const float* __restrict__ W1, const float* __restrict__ g1,
                const float* __restrict__ b1,
                const float* __restrict__ W2n, const float* __restrict__ g2n,
                const float* __restrict__ b2n,
                const uint2* __restrict__ prev, uint2* __restrict__ cur,
                float* __restrict__ sacc, uint2* __restrict__ znext)
{
    __shared__ alignas(16) float sW1[2 * kD * kD];
    __shared__ alignas(16) float sW2[kD * kD];
    __shared__ float scat[kPtsPerBlk][2 * kD + 1];
    __shared__ float stl[kPtsPerBlk][kD + 1];
    __shared__ float sg1[kD], sb1[kD], sg2[kD], sb2[kD];
    const int tid = threadIdx.x;
    for (int i = tid; i < 2 * kD * kD; i += kThreads) sW1[i] = W1[i];
    if (MODE != 3) {
        for (int i = tid; i < kD * kD; i += kThreads) sW2[i] = W2n[i];
    }
    if (tid < kD) {
        sg1[tid] = g1[tid]; sb1[tid] = b1[tid];
        if (MODE != 3) { sg2[tid] = g2n[tid]; sb2[tid] = b2n[tid]; }
    }
    const int s    = tid & 7;
    const int pl   = tid >> 3;
    const int grp  = (tid & 63) & ~7;           // 8-lane group base in wave
    const int point = blockIdx.x * kPtsPerBlk + pl;
    const int base  = point & ~(kN - 1);        // batch offset (b*N)
    const unsigned int pu = idx16[point * 8 + s];
    __syncthreads();

    // gather + online max/sum over 16 neighbours; lane owns 4 channels.
    float mx0 = 0, mx1 = 0, mx2 = 0, mx3 = 0;   // relu output >= 0
    float sm0 = 0, sm1 = 0, sm2 = 0, sm3 = 0;
#pragma unroll
    for (int j = 0; j < 8; ++j) {
        const unsigned int sel = __shfl(pu, grp + j, 64);
        const int r0 = (int)(sel & 0xFFFF);
        const int r1 = (int)(sel >> 16);
        const float4 h0 = unpack_h4(zsrc[(base + r0) * 8 + s]);
        const float4 h1 = unpack_h4(zsrc[(base + r1) * 8 + s]);
        mx0 = fmaxf(mx0, h0.x); sm0 += h0.x;
        mx1 = fmaxf(mx1, h0.y); sm1 += h0.y;
        mx2 = fmaxf(mx2, h0.z); sm2 += h0.z;
        mx3 = fmaxf(mx3, h0.w); sm3 += h0.w;
        mx0 = fmaxf(mx0, h1.x); sm0 += h1.x;
        mx1 = fmaxf(mx1, h1.y); sm1 += h1.y;
        mx2 = fmaxf(mx2, h1.z); sm2 += h1.z;
        mx3 = fmaxf(mx3, h1.w); sm3 += h1.w;
    }
    constexpr float inv = 1.f / kK;
    scat[pl][s * 4 + 0] = mx0; scat[pl][s * 4 + 1] = mx1;
    scat[pl][s * 4 + 2] = mx2; scat[pl][s * 4 + 3] = mx3;
    scat[pl][kD + s * 4 + 0] = sm0 * inv; scat[pl][kD + s * 4 + 1] = sm1 * inv;
    scat[pl][kD + s * 4 + 2] = sm2 * inv; scat[pl][kD + s * 4 + 3] = sm3 * inv;
    __syncthreads();

    // conv2: y = (cat(max,mean) @ W1) * g1 + b1
    float ax = 0, ay = 0, az = 0, aw = 0;
#pragma unroll
    for (int c = 0; c < 2 * kD; ++c) {
        const float cv = scat[pl][c];
        const float4 w = *reinterpret_cast<const float4*>(&sW1[c * kD + s * 4]);
        ax = fmaf(cv, w.x, ax); ay = fmaf(cv, w.y, ay);
        az = fmaf(cv, w.z, az); aw = fmaf(cv, w.w, aw);
    }
    float4 y;
    y.x = fmaf(ax, sg1[s * 4 + 0], sb1[s * 4 + 0]);
    y.y = fmaf(ay, sg1[s * 4 + 1], sb1[s * 4 + 1]);
    y.z = fmaf(az, sg1[s * 4 + 2], sb1[s * 4 + 2]);
    y.w = fmaf(aw, sg1[s * 4 + 3], sb1[s * 4 + 3]);

    const int rb = point * 8 + s;
    float4 t;
    if (MODE == 0) {
        reinterpret_cast<float4*>(sacc)[rb] = y;
        cur[rb] = pack_h4(y.x, y.y, y.z, y.w);
        t.x = lrelu_(y.x); t.y = lrelu_(y.y); t.z = lrelu_(y.z); t.w = lrelu_(y.w);
    } else if (MODE == 1 || MODE == 2) {
        float4 sa = reinterpret_cast<const float4*>(sacc)[rb];
        sa.x += y.x; sa.y += y.y; sa.z += y.z; sa.w += y.w;
        reinterpret_cast<float4*>(sacc)[rb] = sa;
        const float4 pv = unpack_h4(prev[rb]);
        t.x = lrelu_(y.x + pv.x); t.y = lrelu_(y.y + pv.y);
        t.z = lrelu_(y.z + pv.z); t.w = lrelu_(y.w + pv.w);
        if (MODE == 1) cur[rb] = pack_h4(y.x, y.y, y.z, y.w);
    } else {  // MODE == 3: final output
        const float4 sa = reinterpret_cast<const float4*>(sacc)[rb];
        float4 o;
        o.x = lrelu_(sa.x + y.x); o.y = lrelu_(sa.y + y.y);
        o.z = lrelu_(sa.z + y.z); o.w = lrelu_(sa.w + y.w);
        reinterpret_cast<float4*>(sacc)[rb] = o;
        return;
    }

    // next layer's z row: z = relu((t @ W2n) * g2n + b2n), stored fp16
    stl[pl][s * 4 + 0] = t.x; stl[pl][s * 4 + 1] = t.y;
    stl[pl][s * 4 + 2] = t.z; stl[pl][s * 4 + 3] = t.w;
    __syncthreads();
    float zx = 0, zy = 0, zz = 0, zw = 0;
#pragma unroll
    for (int d = 0; d < kD; ++d) {
        const float tv = stl[pl][d];
        const float4 w = *reinterpret_cast<const float4*>(&sW2[d * kD + s * 4]);
        zx = fmaf(tv, w.x, zx); zy = fmaf(tv, w.y, zy);
        zz = fmaf(tv, w.z, zz); zw = fmaf(tv, w.w, zw);
    }
    znext[rb] = pack_h4(
        relu_(fmaf(zx, sg2[s * 4 + 0], sb2[s * 4 + 0])),
        relu_(fmaf(zy, sg2[s * 4 + 1], sb2[s * 4 + 1])),
        relu_(fmaf(zz, sg2[s * 4 + 2], sb2[s * 4 + 2])),
        relu_(fmaf(zw, sg2[s * 4 + 3], sb2[s * 4 + 3])));
}

}  // namespace

extern "C" void kernel_launch(void* const* d_in, const int* in_sizes, int n_in,
                              void* d_out, int out_size, void* d_ws, size_t ws_size,
                              hipStream_t stream)
{
    const float* x   = (const float*)d_in[0];
    const int*   idx = (const int*)d_in[1];
    const float* W2d = (const float*)d_in[2];
    const float* g2  = (const float*)d_in[3];
    const float* b2  = (const float*)d_in[4];
    const float* W1d = (const float*)d_in[5];
    const float* g1  = (const float*)d_in[6];
    const float* b1  = (const float*)d_in[7];
    float* out = (float*)d_out;     // doubles as sacc between dispatches
    char*  ws  = (char*)d_ws;

    // fp16 buffers: one row = 32 halves = 8 uint2 = 64 B
    constexpr size_t kHalfMap = (size_t)kPts * kD * sizeof(__half);  // 8 MB
    uint2* zA = (uint2*)(ws);
    uint2* zB = (uint2*)(ws + kHalfMap);
    uint2* cA = (uint2*)(ws + 2 * kHalfMap);   // x1 (fp16)
    uint2* cB = (uint2*)(ws + 3 * kHalfMap);   // x2 (fp16)
    unsigned int* idx16 = (unsigned int*)(ws + 4 * kHalfMap);  // 4 MB

    const dim3 grid(kBlocks), blk(kThreads);
    zprep_kernel<<<grid, blk, 0, stream>>>(x, idx, W2d, g2, b2, zA, idx16);
    blk_kernel<0><<<grid, blk, 0, stream>>>(zA, idx16, W1d, g1, b1,
        W2d + 1 * kD * kD, g2 + 1 * kD, b2 + 1 * kD, nullptr, cA, out, zB);
    blk_kernel<1><<<grid, blk, 0, stream>>>(zB, idx16,
        W1d + 1 * 2 * kD * kD, g1 + 1 * kD, b1 + 1 * kD,
        W2d + 2 * kD * kD, g2 + 2 * kD, b2 + 2 * kD, cA, cB, out, zA);
    blk_kernel<2><<<grid, blk, 0, stream>>>(zA, idx16,
        W1d + 2 * 2 * kD * kD, g1 + 2 * kD, b1 + 2 * kD,
        W2d + 3 * kD * kD, g2 + 3 * kD, b2 + 3 * kD, cB, nullptr, out, zB);
    blk_kernel<3><<<grid, blk, 0, stream>>>(zB, idx16,
        W1d + 3 * 2 * kD * kD, g1 + 3 * kD, b1 + 3 * kD,
        nullptr, nullptr, nullptr, nullptr, nullptr, out, nullptr);
}